// Round 6
// baseline (35.357 us; speedup 1.0000x reference)
//
#include <hip/hip_runtime.h>
#include <hip/hip_fp16.h>

#define BATCH 4
#define HH 1024
#define WW 1024
#define GDp 8
#define NC 12
#define PAIR2 12    // half2 per z-pair cell: cells (z=p, z=p+1), 48 B, 16-B aligned
#define HROW2 268   // half2 per Hs row: 21*12=252 used, pad to 268 (1072 B)
#define NTILE 4     // 64x16 tiles per block (one 64x64 column)

union V4 { int4 i4; __half2 h[4]; };
typedef float f4 __attribute__((ext_vector_type(4)));

// Persistent column: block 256 thr owns 64x64 px, 4 pipelined 64x16 tiles.
// Round-6 delta: PHASE STAGGER. All blocks launch at t=0 with identical
// phase-lengths and internal barriers -> co-resident blocks stay phase-locked,
// so the CU's LDS bursts and memory edges align (pipes serialize: LDS 58% +
// HBM 52% + VALU 29%, none saturated, dur ~ sum not max). Rotating each
// block's tile order by t0 = f(bid) & 3 offsets co-resident blocks by a full
// tile so their LDS/VALU/memory phases interleave.
__global__ __launch_bounds__(256, 4) void bsa_kernel(
    const float* __restrict__ grid,
    const float* __restrict__ guide,
    const float* __restrict__ image,
    float* __restrict__ out)
{
    __shared__ float sg[GDp][3][3][NC];                     // 3456 B
    __shared__ __align__(16) __half2 Hs2[2][16][HROW2];     // 2 x 17152 B

    const int bx  = blockIdx.x;   // 0..15
    const int byc = blockIdx.y;   // 0..15  (64-row column)
    const int b   = blockIdx.z;
    const int tx = threadIdx.x;   // 0..15
    const int ty = threadIdx.y;   // 0..15
    const int tid = ty * 16 + tx;

    // tile-order stagger: distinct t0 for co-resident blocks under both
    // consecutive-bid and stride-256 co-residency assignments
    const int bid = (b * 16 + byc) * 16 + bx;
    const int t0 = (bid + (bid >> 8)) & 3;

    const int x0  = bx * 64;
    const int y0c = byc * 64;
    const float inv64 = 1.0f / 64.0f;

    // Column y-cell base: rows y0c..y0c+63 have floor(gy) in {ylo, ylo+1}.
    const float gy0c = (y0c + 0.5f) * inv64 - 0.5f;
    const int ylo = (int)floorf(gy0c);

    const int xloc = 4 * tx;
    const size_t plane = (size_t)HH * WW;
    const size_t gpix0 = ((size_t)(b * HH + y0c + ty)) * WW + x0 + xloc;
    const size_t ib0   = (size_t)b * 3 * plane + (size_t)(y0c + ty) * WW + x0 + xloc;

    // ---- pixel IO prefetch (indexed by PHYSICAL tile): tiles t0, t0+1 ----
    f4 G[NTILE], I0[NTILE], I1[NTILE], I2[NTILE];
#pragma unroll
    for (int t = 0; t < 2; ++t) {
        const int p = (t0 + t) & 3;
        const size_t gp = gpix0 + (size_t)p * 16 * WW;
        const size_t ip = ib0   + (size_t)p * 16 * WW;
        G[p]  = *(const f4*)&guide[gp];
        I0[p] = *(const f4*)&image[ip];
        I1[p] = *(const f4*)&image[ip + plane];
        I2[p] = *(const f4*)&image[ip + 2 * plane];
    }

    // ---- stage grid slice once per block: o-pack channel permute ----
    {
        const int z = tid >> 5;        // 0..7
        const int u = tid & 31;        // active u<27
        if (u < 27) {
            const int cell = (u * 11) >> 5;      // u/3 (exact for u<32)
            const int cq   = u - cell * 3;       // u%3 -> channel quad
            const int yy   = (cell * 11) >> 5;   // cell/3 (exact, cell<9)
            const int xx   = cell - yy * 3;
            const int gxi = min(max(bx - 1 + xx, 0), 15);
            const int gyi = min(max(ylo + yy, 0), 15);
            const float* gp = grid + (size_t)b * (NC * GDp * 256)
                                   + ((size_t)z * 16 + gyi) * 16 + gxi;
#pragma unroll
            for (int j = 0; j < 4; ++j) {
                const int c = cq * 4 + j;
                // o-pack perm: pairs (c0,c4)(c1,c5)(c2,c6)(c3,c7)(c8,c9)(c10,c11)
                const int pos = (c < 8) ? ((c & 3) * 2 + (c >> 2)) : c;
                sg[z][yy][xx][pos] = gp[(size_t)c * (GDp * 256)];
            }
        }
    }
    __syncthreads();

    // ---- Hs build for one 16-row tile (physical index) into buffer buf ----
    auto build_hs = [&](int buf, int t) {
        for (int e = tid; e < 384; e += 256) {
            const int r    = e & 15;
            const int cell = e >> 4;        // 0..23 = xs*8 + z
            const int xs   = cell >> 3;
            const int z    = cell & 7;
            const float gy  = (y0c + t * 16 + r + 0.5f) * inv64 - 0.5f;
            const float fyf = floorf(gy);
            const float wy1 = gy - fyf;
            const float wy0 = 1.0f - wy1;
            const int ys0 = (int)fyf - ylo;          // 0 or 1 (column-wide)
            const float* s0 = &sg[z][ys0][xs][0];
            const float* s1 = &sg[z][ys0 + 1][xs][0];
            __half2 h[6];
#pragma unroll
            for (int m = 0; m < 6; ++m) {
                h[m] = __floats2half2_rn(wy0 * s0[2*m]   + wy1 * s1[2*m],
                                         wy0 * s0[2*m+1] + wy1 * s1[2*m+1]);
            }
            __half2* rowp = &Hs2[buf][r][0];
            if (z < 7) {                 // first half of pair p=z
                __half2* hd = rowp + (xs * 7 + z) * PAIR2;
#pragma unroll
                for (int m = 0; m < 6; ++m) hd[m] = h[m];
            }
            if (z > 0) {                 // second half of pair p=z-1
                __half2* hd = rowp + (xs * 7 + (z - 1)) * PAIR2 + 6;
#pragma unroll
                for (int m = 0; m < 6; ++m) hd[m] = h[m];
            }
        }
    };

    build_hs(0, t0);
    __syncthreads();

    const int xs0 = tx >> 3;                     // 0 (x<32) or 1
    const float fxf = (float)(bx - 1 + xs0);
    const float gxb = (x0 + xloc + 0.5f) * inv64 - 0.5f;
    const __half oneh = __float2half_rn(1.0f);

#pragma unroll
    for (int t = 0; t < NTILE; ++t) {
        const int pc = (t0 + t) & 3;             // physical tile this iter

        // ---- prefetch physical tile t0+t+2 ----
        if (t + 2 < NTILE) {
            const int p = (t0 + t + 2) & 3;
            const size_t gp = gpix0 + (size_t)p * 16 * WW;
            const size_t ip = ib0   + (size_t)p * 16 * WW;
            G[p]  = *(const f4*)&guide[gp];
            I0[p] = *(const f4*)&image[ip];
            I1[p] = *(const f4*)&image[ip + plane];
            I2[p] = *(const f4*)&image[ip + 2 * plane];
        }

        // ---- build next physical tile's Hs first (disjoint buffer) ----
        if (t + 1 < NTILE) build_hs((t + 1) & 1, (t0 + t + 1) & 3);

        // ---- per-pixel compute: 4 adjacent x px/thread ----
        const __half2* Hrow = &Hs2[t & 1][ty][0];
        const size_t ib = ib0 + (size_t)pc * 16 * WW;

        const float gk[4]  = {G[pc].x, G[pc].y, G[pc].z, G[pc].w};
        const float ia[4]  = {I0[pc].x, I0[pc].y, I0[pc].z, I0[pc].w};
        const float ja[4]  = {I1[pc].x, I1[pc].y, I1[pc].z, I1[pc].w};
        const float ka[4]  = {I2[pc].x, I2[pc].y, I2[pc].z, I2[pc].w};
        float ok0[4], ok1[4], ok2[4];

#pragma unroll
        for (int k = 0; k < 4; ++k) {
            const float wx1 = (gxb - fxf) + (float)k * inv64;
            const float wx0 = 1.0f - wx1;

            const float gz  = fmaf(gk[k], 8.0f, -0.5f);
            const float fzf = floorf(gz);
            const float zpf = fminf(fmaxf(fzf, 0.0f), 6.0f);      // v_med3
            const float whi = fminf(fmaxf(gz - zpf, 0.0f), 1.0f); // v_med3
            const float wlo = 1.0f - whi;
            const int zp = (int)zpf;

            const __half2 w00 = __float2half2_rn(wx0 * wlo);
            const __half2 w10 = __float2half2_rn(wx0 * whi);
            const __half2 w01 = __float2half2_rn(wx1 * wlo);
            const __half2 w11 = __float2half2_rn(wx1 * whi);

            // z-pair layout: 6 aligned ds_read_b128 cover all 4 corners
            const __half2* q = Hrow + (xs0 * 7 + zp) * PAIR2;
            V4 va, vb, vc, vd, ve, vf;
            va.i4 = *(const int4*)(q);           // A0..A3
            vb.i4 = *(const int4*)(q + 4);       // A4,A5,B0,B1
            vc.i4 = *(const int4*)(q + 8);       // B2..B5
            vd.i4 = *(const int4*)(q + 7 * PAIR2);     // C0..C3
            ve.i4 = *(const int4*)(q + 7 * PAIR2 + 4); // C4,C5,D0,D1
            vf.i4 = *(const int4*)(q + 7 * PAIR2 + 8); // D2..D5

            const __half2 A0 = va.h[0], A1 = va.h[1], A2 = va.h[2], A3 = va.h[3];
            const __half2 A4 = vb.h[0], A5 = vb.h[1];
            const __half2 B0 = vb.h[2], B1 = vb.h[3];
            const __half2 B2 = vc.h[0], B3 = vc.h[1], B4 = vc.h[2], B5 = vc.h[3];
            const __half2 C0 = vd.h[0], C1 = vd.h[1], C2 = vd.h[2], C3 = vd.h[3];
            const __half2 C4 = ve.h[0], C5 = ve.h[1];
            const __half2 D0 = ve.h[2], D1 = ve.h[3];
            const __half2 D2 = vf.h[0], D3 = vf.h[1], D4 = vf.h[2], D5 = vf.h[3];

            const __half2 r0 = __hfma2(w00, A0, __hfma2(w10, B0, __hfma2(w01, C0, __hmul2(w11, D0))));
            const __half2 r1 = __hfma2(w00, A1, __hfma2(w10, B1, __hfma2(w01, C1, __hmul2(w11, D1))));
            const __half2 r2 = __hfma2(w00, A2, __hfma2(w10, B2, __hfma2(w01, C2, __hmul2(w11, D2))));
            const __half2 r3 = __hfma2(w00, A3, __hfma2(w10, B3, __hfma2(w01, C3, __hmul2(w11, D3))));
            const __half2 r4 = __hfma2(w00, A4, __hfma2(w10, B4, __hfma2(w01, C4, __hmul2(w11, D4))));
            const __half2 r5 = __hfma2(w00, A5, __hfma2(w10, B5, __hfma2(w01, C5, __hmul2(w11, D5))));
            // r0=(A00,A10) r1=(A01,A11) r2=(A02,A12) r3=(A03,A13) r4=(A20,A21) r5=(A22,A23)

            const __half i0h = __float2half_rn(ia[k]);
            const __half i1h = __float2half_rn(ja[k]);
            const __half i2h = __float2half_rn(ka[k]);
            const __half2 bi0 = __half2half2(i0h);
            const __half2 bi1 = __half2half2(i1h);
            const __half2 bi2 = __half2half2(i2h);

            const __half2 acc01 = __hfma2(bi0, r0, __hfma2(bi1, r1, __hfma2(bi2, r2, r3)));
            const __half2 d2 = __hfma2(__halves2half2(i0h, i1h), r4,
                                       __hmul2(__halves2half2(i2h, oneh), r5));

            ok0[k] = __low2float(acc01);
            ok1[k] = __high2float(acc01);
            ok2[k] = __half2float(__hadd(__low2half(d2), __high2half(d2)));
        }

        const f4 o0 = {ok0[0], ok0[1], ok0[2], ok0[3]};
        const f4 o1 = {ok1[0], ok1[1], ok1[2], ok1[3]};
        const f4 o2 = {ok2[0], ok2[1], ok2[2], ok2[3]};
        __builtin_nontemporal_store(o0, (f4*)&out[ib]);
        __builtin_nontemporal_store(o1, (f4*)&out[ib + plane]);
        __builtin_nontemporal_store(o2, (f4*)&out[ib + 2 * plane]);

        if (t + 1 < NTILE) __syncthreads();
    }
}

extern "C" void kernel_launch(void* const* d_in, const int* in_sizes, int n_in,
                              void* d_out, int out_size, void* d_ws, size_t ws_size,
                              hipStream_t stream) {
    const float* grid  = (const float*)d_in[0];
    const float* guide = (const float*)d_in[1];
    const float* image = (const float*)d_in[2];
    float* out = (float*)d_out;

    dim3 block(16, 16, 1);
    dim3 grid_dim(WW / 64, HH / 64, BATCH);
    bsa_kernel<<<grid_dim, block, 0, stream>>>(grid, guide, image, out);
}

// Round 7
// 24.751 us; speedup vs baseline: 1.4285x; 1.4285x over previous
//
#include <hip/hip_runtime.h>
#include <hip/hip_fp16.h>

#define BATCH 4
#define HH 1024
#define WW 1024
#define GDp 8
#define NC 12
#define PAIR2 12    // half2 per z-pair cell: cells (z=p, z=p+1), 48 B, 16-B aligned
#define HROW2 268   // half2 per Hs row: 21*12=252 used, pad to 268 (1072 B)
#define NTILE 4     // 64x16 tiles per block (one 64x64 column)

union V4 { int4 i4; __half2 h[4]; };
typedef float f4 __attribute__((ext_vector_type(4)));

// Persistent column: block 256 thr owns 64x64 px, 4 pipelined 64x16 tiles.
// Round-7 delta: WAVE-LOCAL Hs BUILD -> ZERO barriers in the tile loop.
// Wave w only ever reads Hs rows 4w..4w+3 (Hrow = Hs[.][ty], ty in {4w..4w+3}),
// so each wave builds its own 4 rows (96 units/wave = same 1.5 units/lane as
// the cooperative build). Write->read ordering is in-wave lgkmcnt; the only
// __syncthreads left is after the sg stage. Waves free-run and de-phase ->
// no per-tile vmcnt(0)/lgkmcnt(0) barrier drain, cross-pipe overlap improves.
__global__ __launch_bounds__(256, 4) void bsa_kernel(
    const float* __restrict__ grid,
    const float* __restrict__ guide,
    const float* __restrict__ image,
    float* __restrict__ out)
{
    __shared__ float sg[GDp][3][3][NC];                     // 3456 B
    __shared__ __align__(16) __half2 Hs2[2][16][HROW2];     // 2 x 17152 B

    const int bx  = blockIdx.x;   // 0..15
    const int byc = blockIdx.y;   // 0..15  (64-row column)
    const int b   = blockIdx.z;
    const int tx = threadIdx.x;   // 0..15
    const int ty = threadIdx.y;   // 0..15
    const int tid = ty * 16 + tx;
    const int lane = tid & 63;
    const int wv   = tid >> 6;    // wave id: owns Hs rows 4*wv .. 4*wv+3

    const int x0  = bx * 64;
    const int y0c = byc * 64;
    const float inv64 = 1.0f / 64.0f;

    // Column y-cell base: rows y0c..y0c+63 have floor(gy) in {ylo, ylo+1}.
    const float gy0c = (y0c + 0.5f) * inv64 - 0.5f;
    const int ylo = (int)floorf(gy0c);

    const int xloc = 4 * tx;
    const size_t plane = (size_t)HH * WW;
    const size_t gpix0 = ((size_t)(b * HH + y0c + ty)) * WW + x0 + xloc;
    const size_t ib0   = (size_t)b * 3 * plane + (size_t)(y0c + ty) * WW + x0 + xloc;

    // ---- tile-0 pixel IO: in flight under staging + build ----
    f4 cg  = *(const f4*)&guide[gpix0];
    f4 ci0 = *(const f4*)&image[ib0];
    f4 ci1 = *(const f4*)&image[ib0 + plane];
    f4 ci2 = *(const f4*)&image[ib0 + 2 * plane];

    // ---- stage grid slice once per block: o-pack channel permute ----
    {
        const int z = tid >> 5;        // 0..7
        const int u = tid & 31;        // active u<27
        if (u < 27) {
            const int cell = (u * 11) >> 5;      // u/3 (exact for u<32)
            const int cq   = u - cell * 3;       // u%3 -> channel quad
            const int yy   = (cell * 11) >> 5;   // cell/3 (exact, cell<9)
            const int xx   = cell - yy * 3;
            const int gxi = min(max(bx - 1 + xx, 0), 15);
            const int gyi = min(max(ylo + yy, 0), 15);
            const float* gp = grid + (size_t)b * (NC * GDp * 256)
                                   + ((size_t)z * 16 + gyi) * 16 + gxi;
#pragma unroll
            for (int j = 0; j < 4; ++j) {
                const int c = cq * 4 + j;
                // o-pack perm: pairs (c0,c4)(c1,c5)(c2,c6)(c3,c7)(c8,c9)(c10,c11)
                const int pos = (c < 8) ? ((c & 3) * 2 + (c >> 2)) : c;
                sg[z][yy][xx][pos] = gp[(size_t)c * (GDp * 256)];
            }
        }
    }
    __syncthreads();   // the ONLY block-wide barrier

    // ---- wave-local Hs build: wave wv builds rows 4wv..4wv+3 of tile t ----
    auto build_hs = [&](int buf, int t) {
        for (int u = lane; u < 96; u += 64) {
            const int rl   = (u * 171) >> 12;    // u/24 (exact for u<96)
            const int cell = u - rl * 24;        // 0..23 = xs*8 + z
            const int r    = wv * 4 + rl;
            const int xs   = cell >> 3;
            const int z    = cell & 7;
            const float gy  = (y0c + t * 16 + r + 0.5f) * inv64 - 0.5f;
            const float fyf = floorf(gy);
            const float wy1 = gy - fyf;
            const float wy0 = 1.0f - wy1;
            const int ys0 = (int)fyf - ylo;          // 0 or 1 (column-wide)
            const float* s0 = &sg[z][ys0][xs][0];
            const float* s1 = &sg[z][ys0 + 1][xs][0];
            __half2 h[6];
#pragma unroll
            for (int m = 0; m < 6; ++m) {
                h[m] = __floats2half2_rn(wy0 * s0[2*m]   + wy1 * s1[2*m],
                                         wy0 * s0[2*m+1] + wy1 * s1[2*m+1]);
            }
            __half2* rowp = &Hs2[buf][r][0];
            if (z < 7) {                 // first half of pair p=z
                __half2* hd = rowp + (xs * 7 + z) * PAIR2;
#pragma unroll
                for (int m = 0; m < 6; ++m) hd[m] = h[m];
            }
            if (z > 0) {                 // second half of pair p=z-1
                __half2* hd = rowp + (xs * 7 + (z - 1)) * PAIR2 + 6;
#pragma unroll
                for (int m = 0; m < 6; ++m) hd[m] = h[m];
            }
        }
    };

    build_hs(0, 0);    // in-wave lgkmcnt orders writes before this wave's reads

    const int xs0 = tx >> 3;                     // 0 (x<32) or 1
    const float fxf = (float)(bx - 1 + xs0);
    const float gxb = (x0 + xloc + 0.5f) * inv64 - 0.5f;
    const __half oneh = __float2half_rn(1.0f);

#pragma unroll
    for (int t = 0; t < NTILE; ++t) {
        // ---- prefetch next tile's pixel IO (static regs; stays in flight) ----
        f4 ng, ni0, ni1, ni2;
        if (t < NTILE - 1) {
            const size_t gp = gpix0 + (size_t)(t + 1) * 16 * WW;
            const size_t ip = ib0   + (size_t)(t + 1) * 16 * WW;
            ng  = *(const f4*)&guide[gp];
            ni0 = *(const f4*)&image[ip];
            ni1 = *(const f4*)&image[ip + plane];
            ni2 = *(const f4*)&image[ip + 2 * plane];
        }

        // ---- build next tile's Hs (wave-local rows, other buffer) ----
        if (t < NTILE - 1) build_hs((t + 1) & 1, t + 1);

        // ---- per-pixel compute: 4 adjacent x px/thread ----
        const __half2* Hrow = &Hs2[t & 1][ty][0];
        const size_t ib = ib0 + (size_t)t * 16 * WW;

        const float gk[4]  = {cg.x, cg.y, cg.z, cg.w};
        const float ia[4]  = {ci0.x, ci0.y, ci0.z, ci0.w};
        const float ja[4]  = {ci1.x, ci1.y, ci1.z, ci1.w};
        const float ka[4]  = {ci2.x, ci2.y, ci2.z, ci2.w};
        float ok0[4], ok1[4], ok2[4];

#pragma unroll
        for (int k = 0; k < 4; ++k) {
            const float wx1 = (gxb - fxf) + (float)k * inv64;
            const float wx0 = 1.0f - wx1;

            const float gz  = fmaf(gk[k], 8.0f, -0.5f);
            const float fzf = floorf(gz);
            const float zpf = fminf(fmaxf(fzf, 0.0f), 6.0f);      // v_med3
            const float whi = fminf(fmaxf(gz - zpf, 0.0f), 1.0f); // v_med3
            const float wlo = 1.0f - whi;
            const int zp = (int)zpf;

            const __half2 w00 = __float2half2_rn(wx0 * wlo);
            const __half2 w10 = __float2half2_rn(wx0 * whi);
            const __half2 w01 = __float2half2_rn(wx1 * wlo);
            const __half2 w11 = __float2half2_rn(wx1 * whi);

            // z-pair layout: 6 aligned ds_read_b128 cover all 4 corners
            const __half2* q = Hrow + (xs0 * 7 + zp) * PAIR2;
            V4 va, vb, vc, vd, ve, vf;
            va.i4 = *(const int4*)(q);           // A0..A3
            vb.i4 = *(const int4*)(q + 4);       // A4,A5,B0,B1
            vc.i4 = *(const int4*)(q + 8);       // B2..B5
            vd.i4 = *(const int4*)(q + 7 * PAIR2);     // C0..C3
            ve.i4 = *(const int4*)(q + 7 * PAIR2 + 4); // C4,C5,D0,D1
            vf.i4 = *(const int4*)(q + 7 * PAIR2 + 8); // D2..D5

            const __half2 A0 = va.h[0], A1 = va.h[1], A2 = va.h[2], A3 = va.h[3];
            const __half2 A4 = vb.h[0], A5 = vb.h[1];
            const __half2 B0 = vb.h[2], B1 = vb.h[3];
            const __half2 B2 = vc.h[0], B3 = vc.h[1], B4 = vc.h[2], B5 = vc.h[3];
            const __half2 C0 = vd.h[0], C1 = vd.h[1], C2 = vd.h[2], C3 = vd.h[3];
            const __half2 C4 = ve.h[0], C5 = ve.h[1];
            const __half2 D0 = ve.h[2], D1 = ve.h[3];
            const __half2 D2 = vf.h[0], D3 = vf.h[1], D4 = vf.h[2], D5 = vf.h[3];

            const __half2 r0 = __hfma2(w00, A0, __hfma2(w10, B0, __hfma2(w01, C0, __hmul2(w11, D0))));
            const __half2 r1 = __hfma2(w00, A1, __hfma2(w10, B1, __hfma2(w01, C1, __hmul2(w11, D1))));
            const __half2 r2 = __hfma2(w00, A2, __hfma2(w10, B2, __hfma2(w01, C2, __hmul2(w11, D2))));
            const __half2 r3 = __hfma2(w00, A3, __hfma2(w10, B3, __hfma2(w01, C3, __hmul2(w11, D3))));
            const __half2 r4 = __hfma2(w00, A4, __hfma2(w10, B4, __hfma2(w01, C4, __hmul2(w11, D4))));
            const __half2 r5 = __hfma2(w00, A5, __hfma2(w10, B5, __hfma2(w01, C5, __hmul2(w11, D5))));
            // r0=(A00,A10) r1=(A01,A11) r2=(A02,A12) r3=(A03,A13) r4=(A20,A21) r5=(A22,A23)

            const __half i0h = __float2half_rn(ia[k]);
            const __half i1h = __float2half_rn(ja[k]);
            const __half i2h = __float2half_rn(ka[k]);
            const __half2 bi0 = __half2half2(i0h);
            const __half2 bi1 = __half2half2(i1h);
            const __half2 bi2 = __half2half2(i2h);

            const __half2 acc01 = __hfma2(bi0, r0, __hfma2(bi1, r1, __hfma2(bi2, r2, r3)));
            const __half2 d2 = __hfma2(__halves2half2(i0h, i1h), r4,
                                       __hmul2(__halves2half2(i2h, oneh), r5));

            ok0[k] = __low2float(acc01);
            ok1[k] = __high2float(acc01);
            ok2[k] = __half2float(__hadd(__low2half(d2), __high2half(d2)));
        }

        *(f4*)&out[ib]             = f4{ok0[0], ok0[1], ok0[2], ok0[3]};
        *(f4*)&out[ib + plane]     = f4{ok1[0], ok1[1], ok1[2], ok1[3]};
        *(f4*)&out[ib + 2 * plane] = f4{ok2[0], ok2[1], ok2[2], ok2[3]};

        if (t < NTILE - 1) { cg = ng; ci0 = ni0; ci1 = ni1; ci2 = ni2; }
    }
}

extern "C" void kernel_launch(void* const* d_in, const int* in_sizes, int n_in,
                              void* d_out, int out_size, void* d_ws, size_t ws_size,
                              hipStream_t stream) {
    const float* grid  = (const float*)d_in[0];
    const float* guide = (const float*)d_in[1];
    const float* image = (const float*)d_in[2];
    float* out = (float*)d_out;

    dim3 block(16, 16, 1);
    dim3 grid_dim(WW / 64, HH / 64, BATCH);
    bsa_kernel<<<grid_dim, block, 0, stream>>>(grid, guide, image, out);
}